// Round 15
// baseline (201.985 us; speedup 1.0000x reference)
//
#include <hip/hip_runtime.h>
#include <stdint.h>

// OFT injected linear, algebraically reduced:
//   delta is DIAGONAL; diag(Q)=1-2*sum_j S_ij^2 for Cayley of skew S.
//   out = input @ (diag(v) W^T) -- one bf16 MFMA GEMM + cheap prologue.
// GEMM: 256x256 4-phase counted-vmcnt skeleton (115.5us, MfmaUtil 51%,
// 0 bank conflicts) -- best of 6 measured schedule variants (R1-R10),
// 3x reproduced (R5/R11/R12), never failed. FINAL baseline.
// [NT-store experiment dropped: 0/2 infra failures vs baseline 5/5 success.]

typedef __bf16 bf16;
typedef __bf16 bf16x4 __attribute__((ext_vector_type(4)));
typedef __bf16 bf16x8 __attribute__((ext_vector_type(8)));
typedef float  f32x4  __attribute__((ext_vector_type(4)));

#define AS1 __attribute__((address_space(1)))
#define AS3 __attribute__((address_space(3)))

constexpr size_t OFF_INBF = 0;
constexpr size_t OFF_WV   = OFF_INBF + (size_t)4096 * 4096 * 2;
constexpr size_t OFF_MEAN = OFF_WV + (size_t)4096 * 4096 * 2;
constexpr size_t OFF_INFO = OFF_MEAN + 4096 * 4;
constexpr size_t OFF_V    = OFF_INFO + 64;
// TP/NP overlay the Wv region: written by diag, read by vbuild, THEN scaleW
// overwrites Wv. Sequential on one stream -> safe, re-written every replay.
constexpr size_t TP_ELEMS = (size_t)16 * 8192;

// ---------------- K1: column mean over SEQ + fp32->bf16 convert ----------------
__global__ void mean_cvt(const float4* __restrict__ in4, float* __restrict__ meansum,
                         bf16* __restrict__ ob) {
    const int t  = threadIdx.x;
    const int f4 = blockIdx.x * 256 + t;
    const int s0 = blockIdx.y * 32;
    float sx = 0.f, sy = 0.f, sz = 0.f, sw = 0.f;
    for (int s = s0; s < s0 + 32; ++s) {
        float4 vx = in4[(size_t)s * 1024 + f4];
        sx += vx.x; sy += vx.y; sz += vx.z; sw += vx.w;
        bf16x4 bv;
        bv[0] = (bf16)vx.x; bv[1] = (bf16)vx.y; bv[2] = (bf16)vx.z; bv[3] = (bf16)vx.w;
        *(bf16x4*)&ob[(size_t)s * 4096 + f4 * 4] = bv;
    }
    atomicAdd(&meansum[f4 * 4 + 0], sx);
    atomicAdd(&meansum[f4 * 4 + 1], sy);
    atomicAdd(&meansum[f4 * 4 + 2], sz);
    atomicAdd(&meansum[f4 * 4 + 3], sw);
}

// ---------------- K2: logits -> softmax -> top-k selection ----------------
__global__ void omega_kernel(const float* __restrict__ meansum, const float* __restrict__ lora_route,
                             const int* __restrict__ task_id_p, int* __restrict__ info_i,
                             float* __restrict__ info_f) {
    __shared__ float red[256];
    __shared__ float logits[5];
    const int t = threadIdx.x;
    const int tid = task_id_p[0];
    const float* route = lora_route + (size_t)(tid - 1) * 4096 * 5;
    float acc[5] = {0.f, 0.f, 0.f, 0.f, 0.f};
    for (int f = t; f < 4096; f += 256) {
        float m = meansum[f] * (1.0f / 4096.0f);
#pragma unroll
        for (int p = 0; p < 5; ++p) acc[p] += m * route[f * 5 + p];
    }
    for (int p = 0; p < 5; ++p) {
        red[t] = acc[p];
        __syncthreads();
        for (int s = 128; s > 0; s >>= 1) {
            if (t < s) red[t] += red[t + s];
            __syncthreads();
        }
        if (t == 0) logits[p] = red[0];
        __syncthreads();
    }
    if (t == 0) {
        float mx = logits[0];
        for (int p = 1; p < 5; ++p) mx = fmaxf(mx, logits[p]);
        float e[5], se = 0.f;
        for (int p = 0; p < 5; ++p) { e[p] = expf(logits[p] - mx); se += e[p]; }
        float om[5];
        for (int p = 0; p < 5; ++p) om[p] = e[p] / se;
        const int n = tid < 5 ? tid : 5;
        int j1 = 0;
        for (int p = 1; p < n; ++p) if (om[p] > om[j1]) j1 = p;
        int j2 = -1;
        for (int p = 0; p < n; ++p) if (p != j1 && (j2 < 0 || om[p] > om[j2])) j2 = p;
        const int k = tid < 2 ? tid : 2;
        info_i[0] = j1;
        info_i[1] = (k > 1) ? j2 : j1;
        info_i[2] = k;
        float c = om[j1];
        if (k > 1) c *= om[j2];
        info_f[3] = c;
    }
}

// ------- K3: per (task, block, row-tile a, col-tile b): PARTIAL T and nrm2, no atomics -------
__global__ void diag_kernel(const float* __restrict__ lora_down, const int* __restrict__ info_i,
                            float* __restrict__ TP, float* __restrict__ NP) {
    const int bid = blockIdx.x;        // 2048 = ts(2) x rb(4) x a(16) x b(16)
    const int ts = bid >> 10;
    const int rb = (bid >> 8) & 3;
    const int a  = (bid >> 4) & 15;
    const int b  = bid & 15;
    const int k = info_i[2];
    if (ts >= k) return;
    const int j = info_i[ts];
    const float* R = lora_down + ((size_t)(j * 4 + rb) << 20);
    __shared__ float X[64][65];
    __shared__ float Y[64][65];
    __shared__ float wsum[4];
    const int t = threadIdx.x;
    const int i = t >> 2, g = t & 3;
    const int a64 = a * 64, b64 = b * 64;
    float nacc = 0.f;
#pragma unroll
    for (int qq = 0; qq < 4; ++qq) {
        const int fi = qq * 256 + t;
        const int row = fi >> 4, c4 = fi & 15;
        float4 vx = *(const float4*)&R[(size_t)(a64 + row) * 1024 + b64 + c4 * 4];
        X[row][c4 * 4 + 0] = vx.x; X[row][c4 * 4 + 1] = vx.y;
        X[row][c4 * 4 + 2] = vx.z; X[row][c4 * 4 + 3] = vx.w;
        nacc += vx.x * vx.x + vx.y * vx.y + vx.z * vx.z + vx.w * vx.w;
        float4 vy = *(const float4*)&R[(size_t)(b64 + row) * 1024 + a64 + c4 * 4];
        Y[row][c4 * 4 + 0] = vy.x; Y[row][c4 * 4 + 1] = vy.y;
        Y[row][c4 * 4 + 2] = vy.z; Y[row][c4 * 4 + 3] = vy.w;
    }
    __syncthreads();
    float tacc = 0.f;
#pragma unroll
    for (int s = 0; s < 16; ++s) {
        float d = X[i][g * 16 + s] - Y[g * 16 + s][i];
        tacc += d * d;
    }
    tacc += __shfl_xor(tacc, 1);
    tacc += __shfl_xor(tacc, 2);
    if (g == 0) TP[b * 8192 + ((ts * 4 + rb) << 10) + a64 + i] = tacc;
    for (int off = 32; off > 0; off >>= 1) nacc += __shfl_down(nacc, off);
    if ((t & 63) == 0) wsum[t >> 6] = nacc;
    __syncthreads();
    if (t == 0) NP[(ts * 4 + rb) * 256 + a * 16 + b] = wsum[0] + wsum[1] + wsum[2] + wsum[3];
}

// ---------------- K4: reduce partials; v[i] = c * prod_ts (1 - 0.5*scale^2*T) ----------------
__global__ void vbuild(const float* __restrict__ TP, const float* __restrict__ NP,
                       const int* __restrict__ info_i, const float* __restrict__ info_f,
                       float* __restrict__ v) {
    __shared__ float red[256];
    __shared__ float snrm[8];
    const int t = threadIdx.x;
    for (int g = 0; g < 8; ++g) {
        red[t] = NP[g * 256 + t];
        __syncthreads();
        for (int s = 128; s > 0; s >>= 1) {
            if (t < s) red[t] += red[t + s];
            __syncthreads();
        }
        if (t == 0) snrm[g] = red[0];
        __syncthreads();
    }
    const int i = blockIdx.x * 256 + t;
    const int k = info_i[2];
    const float c = info_f[3];
    const int rb = i >> 10, di = i & 1023;
    const float eps = 1e-5f * 1024.0f * 1024.0f / 2.0f;
    float q = c;
    for (int ts = 0; ts < k; ++ts) {
        float tt = 0.f;
#pragma unroll
        for (int bb = 0; bb < 16; ++bb) tt += TP[bb * 8192 + ((ts * 4 + rb) << 10) + di];
        float nrm = sqrtf(snrm[ts * 4 + rb]);
        float scale = (nrm <= eps) ? 1.0f : eps / fmaxf(nrm, 1e-12f);
        q *= 1.0f - 0.5f * scale * scale * tt;
    }
    v[i] = q;
}

// ---------------- K5: Wv[o][i] = bf16(W[o][i] * v[i]) ----------------
__global__ void scaleW(const float4* __restrict__ W4, const float* __restrict__ v,
                       bf16* __restrict__ Wv) {
    const size_t stride = (size_t)gridDim.x * blockDim.x;
    for (size_t i = (size_t)blockIdx.x * blockDim.x + threadIdx.x; i < (size_t)4096 * 1024; i += stride) {
        float4 w = W4[i];
        const float* vp = &v[(i & 1023) << 2];
        bf16x4 o;
        o[0] = (bf16)(w.x * vp[0]);
        o[1] = (bf16)(w.y * vp[1]);
        o[2] = (bf16)(w.z * vp[2]);
        o[3] = (bf16)(w.w * vp[3]);
        *(bf16x4*)&Wv[i << 2] = o;
    }
}

// ---------------- K6: 256^2-tile 4-phase bf16 GEMM, C = A @ B^T (f32 out) ----------------
// ds_reads 8/8/4/4, one-phase-ahead operand reads, counted vmcnt, T1/T2/T5.
__device__ __forceinline__ void gload_lds16(const bf16* g, bf16* lds) {
    __builtin_amdgcn_global_load_lds((const AS1 void*)g, (AS3 void*)lds, 16, 0, 0);
}

__global__ __launch_bounds__(512, 2) void gemm256(const bf16* __restrict__ A,
                                                  const bf16* __restrict__ B,
                                                  float* __restrict__ C) {
    __shared__ bf16 lds[65536];   // 128 KiB: 2 buffers x (A 32KB + B 32KB)
    const int t = threadIdx.x;
    const int w = t >> 6, l = t & 63;
    const int bid = blockIdx.x;
    const int swz = ((bid & 7) << 5) | (bid >> 3);   // T1 (256 % 8 == 0)
    const int bm = swz >> 4, bn = swz & 15;
    const int wm = w >> 2, wn = w & 3;               // 2M x 4N waves
    const int rl = l & 15, q = l >> 4;
    const int xm = (l & 7) << 4;                     // T2 swizzle (byte bits 4-6)

    const int srow = (w << 4) + (l >> 3);
    const int scol = ((l & 7) ^ (l >> 3)) << 3;      // pre-swizzled global col
    const bf16* pA = A + (size_t)((bm << 8) + srow) * 4096 + scol;
    const bf16* pB = B + (size_t)((bn << 8) + srow) * 4096 + scol;

#define STG(dstE, srcP, h, kt) do {                                                          \
        gload_lds16((srcP) + (size_t)((h) * 128) * 4096 + (size_t)(kt) * 64,                 \
                    (bf16*)&lds[(dstE) + (h) * 8192 + w * 1024]);                            \
        gload_lds16((srcP) + (size_t)((h) * 128 + 8) * 4096 + (size_t)(kt) * 64,             \
                    (bf16*)&lds[(dstE) + (h) * 8192 + w * 1024 + 512]);                      \
    } while (0)

    const int aB = (((wm << 7) + rl) << 6);
    const int bB = 16384 + (((wn << 6) + rl) << 6);
    const int c0 = (((q << 4) + 0) ^ xm) >> 1;
    const int c1 = (((q << 4) + 64) ^ xm) >> 1;

    f32x4 acc[8][4] = {};
    bf16x8 a0L[4], a0H[4], a1L[4], a1H[4], b0[4], b1[4], a0n[4];

    // prologue: A(0),B(0) -> buf0; A(1) -> buf1   (12 loads/wave)
    STG(0, pA, 0, 0); STG(0, pA, 1, 0);
    STG(16384, pB, 0, 0); STG(16384, pB, 1, 0);
    STG(32768, pA, 0, 1); STG(32768, pA, 1, 1);
    asm volatile("s_waitcnt vmcnt(8)" ::: "memory");
    __builtin_amdgcn_s_barrier();
    asm volatile("" ::: "memory");
#pragma unroll
    for (int m = 0; m < 4; ++m) a0L[m] = *(const bf16x8*)&lds[0 + aB + m * 1024 + c0];

    for (int kt = 0; kt < 64; ++kt) {
        const int cur = (kt & 1) << 15;
        const int nxt = cur ^ 32768;
        if (kt < 63) asm volatile("s_waitcnt vmcnt(4)" ::: "memory");
        else         asm volatile("s_waitcnt vmcnt(0)" ::: "memory");
        __builtin_amdgcn_s_barrier();
        asm volatile("" ::: "memory");

        // ---- P0: read b0[4], a0H[4]; stage B0(kt+1)->nxt; MFMA G0 = m0-3 x k0
#pragma unroll
        for (int n = 0; n < 4; ++n) b0[n] = *(const bf16x8*)&lds[cur + bB + n * 1024 + c0];
#pragma unroll
        for (int m = 0; m < 4; ++m) a0H[m] = *(const bf16x8*)&lds[cur + aB + (m + 4) * 1024 + c0];
        if (kt + 1 < 64) STG(nxt + 16384, pB, 0, kt + 1);
        __builtin_amdgcn_s_setprio(1);
#pragma unroll
        for (int m = 0; m < 4; ++m)
#pragma unroll
            for (int n = 0; n < 4; ++n)
                acc[m][n] = __builtin_amdgcn_mfma_f32_16x16x32_bf16(a0L[m], b0[n], acc[m][n], 0, 0, 0);
        __builtin_amdgcn_s_setprio(0);
        __builtin_amdgcn_s_barrier();

        // ---- P1: read a1L[4], b1[4]; stage B1(kt+1)->nxt; MFMA G1 = m4-7 x k0
#pragma unroll
        for (int m = 0; m < 4; ++m) a1L[m] = *(const bf16x8*)&lds[cur + aB + m * 1024 + c1];
#pragma unroll
        for (int n = 0; n < 4; ++n) b1[n] = *(const bf16x8*)&lds[cur + bB + n * 1024 + c1];
        if (kt + 1 < 64) STG(nxt + 16384, pB, 1, kt + 1);
        __builtin_amdgcn_s_setprio(1);
#pragma unroll
        for (int m = 0; m < 4; ++m)
#pragma unroll
            for (int n = 0; n < 4; ++n)
                acc[m + 4][n] = __builtin_amdgcn_mfma_f32_16x16x32_bf16(a0H[m], b0[n], acc[m + 4][n], 0, 0, 0);
        __builtin_amdgcn_s_setprio(0);
        __builtin_amdgcn_s_barrier();

        // ---- P2: read a1H[4]; MFMA G2 = m0-3 x k1; drain reads + A(kt+1)
#pragma unroll
        for (int m = 0; m < 4; ++m) a1H[m] = *(const bf16x8*)&lds[cur + aB + (m + 4) * 1024 + c1];
        __builtin_amdgcn_s_setprio(1);
#pragma unroll
        for (int m = 0; m < 4; ++m)
#pragma unroll
            for (int n = 0; n < 4; ++n)
                acc[m][n] = __builtin_amdgcn_mfma_f32_16x16x32_bf16(a1L[m], b1[n], acc[m][n], 0, 0, 0);
        __builtin_amdgcn_s_setprio(0);
        asm volatile("s_waitcnt lgkmcnt(0)" ::: "memory");
        if (kt < 63) asm volatile("s_waitcnt vmcnt(4)" ::: "memory");
        __builtin_amdgcn_s_barrier();
        asm volatile("" ::: "memory");

        // ---- P3: stage A0,A1(kt+2)->cur; read a0L(kt+1) from nxt; MFMA G3 = m4-7 x k1
        if (kt + 2 < 64) { STG(cur, pA, 0, kt + 2); STG(cur, pA, 1, kt + 2); }
        if (kt + 1 < 64) {
#pragma unroll
            for (int m = 0; m < 4; ++m) a0n[m] = *(const bf16x8*)&lds[nxt + aB + m * 1024 + c0];
        }
        __builtin_amdgcn_s_setprio(1);
#pragma unroll
        for (int m = 0; m < 4; ++m)
#pragma unroll
            for (int n = 0; n < 4; ++n)
                acc[m + 4][n] = __builtin_amdgcn_mfma_f32_16x16x32_bf16(a1H[m], b1[n], acc[m + 4][n], 0, 0, 0);
        __builtin_amdgcn_s_setprio(0);
        if (kt + 1 < 64) {
#pragma unroll
            for (int m = 0; m < 4; ++m) a0L[m] = a0n[m];
        }
    }
#undef STG

    // epilogue: C row = 16m + 4q + r, col = 16n + rl (m89 layout)
    const int crow = (bm << 8) + (wm << 7) + (q << 2);
    const int ccol = (bn << 8) + (wn << 6) + rl;
#pragma unroll
    for (int m = 0; m < 8; ++m)
#pragma unroll
        for (int n = 0; n < 4; ++n)
#pragma unroll
            for (int r = 0; r < 4; ++r)
                C[(size_t)(crow + m * 16 + r) * 4096 + ccol + n * 16] = acc[m][n][r];
}

extern "C" void kernel_launch(void* const* d_in, const int* in_sizes, int n_in,
                              void* d_out, int out_size, void* d_ws, size_t ws_size,
                              hipStream_t stream) {
    const float* input      = (const float*)d_in[0];
    const float* lora_route = (const float*)d_in[1];
    const float* lora_down  = (const float*)d_in[2];
    const float* W          = (const float*)d_in[3];
    const int*   task_id    = (const int*)d_in[4];

    char* ws = (char*)d_ws;
    bf16*  inbf    = (bf16*)(ws + OFF_INBF);
    bf16*  Wv      = (bf16*)(ws + OFF_WV);
    float* meansum = (float*)(ws + OFF_MEAN);
    int*   info_i  = (int*)(ws + OFF_INFO);
    float* info_f  = (float*)(ws + OFF_INFO);
    float* v       = (float*)(ws + OFF_V);
    // TP/NP overlay Wv (consumed by vbuild before scaleW writes Wv)
    float* TP      = (float*)(ws + OFF_WV);
    float* NP      = TP + TP_ELEMS;
    float* out     = (float*)d_out;

    hipMemsetAsync(meansum, 0, 4096 * 4, stream);

    mean_cvt<<<dim3(4, 128), 256, 0, stream>>>((const float4*)input, meansum, inbf);
    omega_kernel<<<1, 256, 0, stream>>>(meansum, lora_route, task_id, info_i, info_f);
    diag_kernel<<<2048, 256, 0, stream>>>(lora_down, info_i, TP, NP);
    vbuild<<<16, 256, 0, stream>>>(TP, NP, info_i, info_f, v);
    scaleW<<<4096, 256, 0, stream>>>((const float4*)W, v, Wv);
    gemm256<<<256, 512, 0, stream>>>(inbf, Wv, out);
}

// Round 16
// 197.852 us; speedup vs baseline: 1.0209x; 1.0209x over previous
//
#include <hip/hip_runtime.h>
#include <stdint.h>

// OFT injected linear, algebraically reduced:
//   delta is DIAGONAL; diag(Q)=1-2*sum_j S_ij^2 for Cayley of skew S.
//   out = input @ (diag(v) W^T) -- one bf16 MFMA GEMM + cheap prologue.
// GEMM: 256x256 4-phase counted-vmcnt skeleton (115.5us, MfmaUtil 51%,
// 0 bank conflicts; 4x reproduced R5/R11/R12/R15)
// + NONTEMPORAL C stores (keep L2 clean for A/B staging re-reads;
// FETCH_SIZE 147.5MB vs 64MB ideal says C write-allocate evicts tiles).
// [R13/R14 were push-phase infra flakes -- kernel never executed; the
//  container is confirmed healthy again as of R15.]

typedef __bf16 bf16;
typedef __bf16 bf16x4 __attribute__((ext_vector_type(4)));
typedef __bf16 bf16x8 __attribute__((ext_vector_type(8)));
typedef float  f32x4  __attribute__((ext_vector_type(4)));

#define AS1 __attribute__((address_space(1)))
#define AS3 __attribute__((address_space(3)))

constexpr size_t OFF_INBF = 0;
constexpr size_t OFF_WV   = OFF_INBF + (size_t)4096 * 4096 * 2;
constexpr size_t OFF_MEAN = OFF_WV + (size_t)4096 * 4096 * 2;
constexpr size_t OFF_INFO = OFF_MEAN + 4096 * 4;
constexpr size_t OFF_V    = OFF_INFO + 64;
// TP/NP overlay the Wv region: written by diag, read by vbuild, THEN scaleW
// overwrites Wv. Sequential on one stream -> safe, re-written every replay.
constexpr size_t TP_ELEMS = (size_t)16 * 8192;

// ---------------- K1: column mean over SEQ + fp32->bf16 convert ----------------
__global__ void mean_cvt(const float4* __restrict__ in4, float* __restrict__ meansum,
                         bf16* __restrict__ ob) {
    const int t  = threadIdx.x;
    const int f4 = blockIdx.x * 256 + t;
    const int s0 = blockIdx.y * 32;
    float sx = 0.f, sy = 0.f, sz = 0.f, sw = 0.f;
    for (int s = s0; s < s0 + 32; ++s) {
        float4 vx = in4[(size_t)s * 1024 + f4];
        sx += vx.x; sy += vx.y; sz += vx.z; sw += vx.w;
        bf16x4 bv;
        bv[0] = (bf16)vx.x; bv[1] = (bf16)vx.y; bv[2] = (bf16)vx.z; bv[3] = (bf16)vx.w;
        *(bf16x4*)&ob[(size_t)s * 4096 + f4 * 4] = bv;
    }
    atomicAdd(&meansum[f4 * 4 + 0], sx);
    atomicAdd(&meansum[f4 * 4 + 1], sy);
    atomicAdd(&meansum[f4 * 4 + 2], sz);
    atomicAdd(&meansum[f4 * 4 + 3], sw);
}

// ---------------- K2: logits -> softmax -> top-k selection ----------------
__global__ void omega_kernel(const float* __restrict__ meansum, const float* __restrict__ lora_route,
                             const int* __restrict__ task_id_p, int* __restrict__ info_i,
                             float* __restrict__ info_f) {
    __shared__ float red[256];
    __shared__ float logits[5];
    const int t = threadIdx.x;
    const int tid = task_id_p[0];
    const float* route = lora_route + (size_t)(tid - 1) * 4096 * 5;
    float acc[5] = {0.f, 0.f, 0.f, 0.f, 0.f};
    for (int f = t; f < 4096; f += 256) {
        float m = meansum[f] * (1.0f / 4096.0f);
#pragma unroll
        for (int p = 0; p < 5; ++p) acc[p] += m * route[f * 5 + p];
    }
    for (int p = 0; p < 5; ++p) {
        red[t] = acc[p];
        __syncthreads();
        for (int s = 128; s > 0; s >>= 1) {
            if (t < s) red[t] += red[t + s];
            __syncthreads();
        }
        if (t == 0) logits[p] = red[0];
        __syncthreads();
    }
    if (t == 0) {
        float mx = logits[0];
        for (int p = 1; p < 5; ++p) mx = fmaxf(mx, logits[p]);
        float e[5], se = 0.f;
        for (int p = 0; p < 5; ++p) { e[p] = expf(logits[p] - mx); se += e[p]; }
        float om[5];
        for (int p = 0; p < 5; ++p) om[p] = e[p] / se;
        const int n = tid < 5 ? tid : 5;
        int j1 = 0;
        for (int p = 1; p < n; ++p) if (om[p] > om[j1]) j1 = p;
        int j2 = -1;
        for (int p = 0; p < n; ++p) if (p != j1 && (j2 < 0 || om[p] > om[j2])) j2 = p;
        const int k = tid < 2 ? tid : 2;
        info_i[0] = j1;
        info_i[1] = (k > 1) ? j2 : j1;
        info_i[2] = k;
        float c = om[j1];
        if (k > 1) c *= om[j2];
        info_f[3] = c;
    }
}

// ------- K3: per (task, block, row-tile a, col-tile b): PARTIAL T and nrm2, no atomics -------
__global__ void diag_kernel(const float* __restrict__ lora_down, const int* __restrict__ info_i,
                            float* __restrict__ TP, float* __restrict__ NP) {
    const int bid = blockIdx.x;        // 2048 = ts(2) x rb(4) x a(16) x b(16)
    const int ts = bid >> 10;
    const int rb = (bid >> 8) & 3;
    const int a  = (bid >> 4) & 15;
    const int b  = bid & 15;
    const int k = info_i[2];
    if (ts >= k) return;
    const int j = info_i[ts];
    const float* R = lora_down + ((size_t)(j * 4 + rb) << 20);
    __shared__ float X[64][65];
    __shared__ float Y[64][65];
    __shared__ float wsum[4];
    const int t = threadIdx.x;
    const int i = t >> 2, g = t & 3;
    const int a64 = a * 64, b64 = b * 64;
    float nacc = 0.f;
#pragma unroll
    for (int qq = 0; qq < 4; ++qq) {
        const int fi = qq * 256 + t;
        const int row = fi >> 4, c4 = fi & 15;
        float4 vx = *(const float4*)&R[(size_t)(a64 + row) * 1024 + b64 + c4 * 4];
        X[row][c4 * 4 + 0] = vx.x; X[row][c4 * 4 + 1] = vx.y;
        X[row][c4 * 4 + 2] = vx.z; X[row][c4 * 4 + 3] = vx.w;
        nacc += vx.x * vx.x + vx.y * vx.y + vx.z * vx.z + vx.w * vx.w;
        float4 vy = *(const float4*)&R[(size_t)(b64 + row) * 1024 + a64 + c4 * 4];
        Y[row][c4 * 4 + 0] = vy.x; Y[row][c4 * 4 + 1] = vy.y;
        Y[row][c4 * 4 + 2] = vy.z; Y[row][c4 * 4 + 3] = vy.w;
    }
    __syncthreads();
    float tacc = 0.f;
#pragma unroll
    for (int s = 0; s < 16; ++s) {
        float d = X[i][g * 16 + s] - Y[g * 16 + s][i];
        tacc += d * d;
    }
    tacc += __shfl_xor(tacc, 1);
    tacc += __shfl_xor(tacc, 2);
    if (g == 0) TP[b * 8192 + ((ts * 4 + rb) << 10) + a64 + i] = tacc;
    for (int off = 32; off > 0; off >>= 1) nacc += __shfl_down(nacc, off);
    if ((t & 63) == 0) wsum[t >> 6] = nacc;
    __syncthreads();
    if (t == 0) NP[(ts * 4 + rb) * 256 + a * 16 + b] = wsum[0] + wsum[1] + wsum[2] + wsum[3];
}

// ---------------- K4: reduce partials; v[i] = c * prod_ts (1 - 0.5*scale^2*T) ----------------
__global__ void vbuild(const float* __restrict__ TP, const float* __restrict__ NP,
                       const int* __restrict__ info_i, const float* __restrict__ info_f,
                       float* __restrict__ v) {
    __shared__ float red[256];
    __shared__ float snrm[8];
    const int t = threadIdx.x;
    for (int g = 0; g < 8; ++g) {
        red[t] = NP[g * 256 + t];
        __syncthreads();
        for (int s = 128; s > 0; s >>= 1) {
            if (t < s) red[t] += red[t + s];
            __syncthreads();
        }
        if (t == 0) snrm[g] = red[0];
        __syncthreads();
    }
    const int i = blockIdx.x * 256 + t;
    const int k = info_i[2];
    const float c = info_f[3];
    const int rb = i >> 10, di = i & 1023;
    const float eps = 1e-5f * 1024.0f * 1024.0f / 2.0f;
    float q = c;
    for (int ts = 0; ts < k; ++ts) {
        float tt = 0.f;
#pragma unroll
        for (int bb = 0; bb < 16; ++bb) tt += TP[bb * 8192 + ((ts * 4 + rb) << 10) + di];
        float nrm = sqrtf(snrm[ts * 4 + rb]);
        float scale = (nrm <= eps) ? 1.0f : eps / fmaxf(nrm, 1e-12f);
        q *= 1.0f - 0.5f * scale * scale * tt;
    }
    v[i] = q;
}

// ---------------- K5: Wv[o][i] = bf16(W[o][i] * v[i]) ----------------
__global__ void scaleW(const float4* __restrict__ W4, const float* __restrict__ v,
                       bf16* __restrict__ Wv) {
    const size_t stride = (size_t)gridDim.x * blockDim.x;
    for (size_t i = (size_t)blockIdx.x * blockDim.x + threadIdx.x; i < (size_t)4096 * 1024; i += stride) {
        float4 w = W4[i];
        const float* vp = &v[(i & 1023) << 2];
        bf16x4 o;
        o[0] = (bf16)(w.x * vp[0]);
        o[1] = (bf16)(w.y * vp[1]);
        o[2] = (bf16)(w.z * vp[2]);
        o[3] = (bf16)(w.w * vp[3]);
        *(bf16x4*)&Wv[i << 2] = o;
    }
}

// ---------------- K6: 256^2-tile 4-phase bf16 GEMM, C = A @ B^T (f32 out) ----------------
// ds_reads 8/8/4/4, one-phase-ahead operand reads, counted vmcnt, T1/T2/T5.
// Epilogue: NONTEMPORAL stores -- C (64MB) must not evict A/B staging tiles
// from the 4MB-per-XCD L2 (FETCH_SIZE showed 2.3x re-read of A/B).
__device__ __forceinline__ void gload_lds16(const bf16* g, bf16* lds) {
    __builtin_amdgcn_global_load_lds((const AS1 void*)g, (AS3 void*)lds, 16, 0, 0);
}

__global__ __launch_bounds__(512, 2) void gemm256(const bf16* __restrict__ A,
                                                  const bf16* __restrict__ B,
                                                  float* __restrict__ C) {
    __shared__ bf16 lds[65536];   // 128 KiB: 2 buffers x (A 32KB + B 32KB)
    const int t = threadIdx.x;
    const int w = t >> 6, l = t & 63;
    const int bid = blockIdx.x;
    const int swz = ((bid & 7) << 5) | (bid >> 3);   // T1 (256 % 8 == 0)
    const int bm = swz >> 4, bn = swz & 15;
    const int wm = w >> 2, wn = w & 3;               // 2M x 4N waves
    const int rl = l & 15, q = l >> 4;
    const int xm = (l & 7) << 4;                     // T2 swizzle (byte bits 4-6)

    const int srow = (w << 4) + (l >> 3);
    const int scol = ((l & 7) ^ (l >> 3)) << 3;      // pre-swizzled global col
    const bf16* pA = A + (size_t)((bm << 8) + srow) * 4096 + scol;
    const bf16* pB = B + (size_t)((bn << 8) + srow) * 4096 + scol;

#define STG(dstE, srcP, h, kt) do {                                                          \
        gload_lds16((srcP) + (size_t)((h) * 128) * 4096 + (size_t)(kt) * 64,                 \
                    (bf16*)&lds[(dstE) + (h) * 8192 + w * 1024]);                            \
        gload_lds16((srcP) + (size_t)((h) * 128 + 8) * 4096 + (size_t)(kt) * 64,             \
                    (bf16*)&lds[(dstE) + (h) * 8192 + w * 1024 + 512]);                      \
    } while (0)

    const int aB = (((wm << 7) + rl) << 6);
    const int bB = 16384 + (((wn << 6) + rl) << 6);
    const int c0 = (((q << 4) + 0) ^ xm) >> 1;
    const int c1 = (((q << 4) + 64) ^ xm) >> 1;

    f32x4 acc[8][4] = {};
    bf16x8 a0L[4], a0H[4], a1L[4], a1H[4], b0[4], b1[4], a0n[4];

    // prologue: A(0),B(0) -> buf0; A(1) -> buf1   (12 loads/wave)
    STG(0, pA, 0, 0); STG(0, pA, 1, 0);
    STG(16384, pB, 0, 0); STG(16384, pB, 1, 0);
    STG(32768, pA, 0, 1); STG(32768, pA, 1, 1);
    asm volatile("s_waitcnt vmcnt(8)" ::: "memory");
    __builtin_amdgcn_s_barrier();
    asm volatile("" ::: "memory");
#pragma unroll
    for (int m = 0; m < 4; ++m) a0L[m] = *(const bf16x8*)&lds[0 + aB + m * 1024 + c0];

    for (int kt = 0; kt < 64; ++kt) {
        const int cur = (kt & 1) << 15;
        const int nxt = cur ^ 32768;
        if (kt < 63) asm volatile("s_waitcnt vmcnt(4)" ::: "memory");
        else         asm volatile("s_waitcnt vmcnt(0)" ::: "memory");
        __builtin_amdgcn_s_barrier();
        asm volatile("" ::: "memory");

        // ---- P0: read b0[4], a0H[4]; stage B0(kt+1)->nxt; MFMA G0 = m0-3 x k0
#pragma unroll
        for (int n = 0; n < 4; ++n) b0[n] = *(const bf16x8*)&lds[cur + bB + n * 1024 + c0];
#pragma unroll
        for (int m = 0; m < 4; ++m) a0H[m] = *(const bf16x8*)&lds[cur + aB + (m + 4) * 1024 + c0];
        if (kt + 1 < 64) STG(nxt + 16384, pB, 0, kt + 1);
        __builtin_amdgcn_s_setprio(1);
#pragma unroll
        for (int m = 0; m < 4; ++m)
#pragma unroll
            for (int n = 0; n < 4; ++n)
                acc[m][n] = __builtin_amdgcn_mfma_f32_16x16x32_bf16(a0L[m], b0[n], acc[m][n], 0, 0, 0);
        __builtin_amdgcn_s_setprio(0);
        __builtin_amdgcn_s_barrier();

        // ---- P1: read a1L[4], b1[4]; stage B1(kt+1)->nxt; MFMA G1 = m4-7 x k0
#pragma unroll
        for (int m = 0; m < 4; ++m) a1L[m] = *(const bf16x8*)&lds[cur + aB + m * 1024 + c1];
#pragma unroll
        for (int n = 0; n < 4; ++n) b1[n] = *(const bf16x8*)&lds[cur + bB + n * 1024 + c1];
        if (kt + 1 < 64) STG(nxt + 16384, pB, 1, kt + 1);
        __builtin_amdgcn_s_setprio(1);
#pragma unroll
        for (int m = 0; m < 4; ++m)
#pragma unroll
            for (int n = 0; n < 4; ++n)
                acc[m + 4][n] = __builtin_amdgcn_mfma_f32_16x16x32_bf16(a0H[m], b0[n], acc[m + 4][n], 0, 0, 0);
        __builtin_amdgcn_s_setprio(0);
        __builtin_amdgcn_s_barrier();

        // ---- P2: read a1H[4]; MFMA G2 = m0-3 x k1; drain reads + A(kt+1)
#pragma unroll
        for (int m = 0; m < 4; ++m) a1H[m] = *(const bf16x8*)&lds[cur + aB + (m + 4) * 1024 + c1];
        __builtin_amdgcn_s_setprio(1);
#pragma unroll
        for (int m = 0; m < 4; ++m)
#pragma unroll
            for (int n = 0; n < 4; ++n)
                acc[m][n] = __builtin_amdgcn_mfma_f32_16x16x32_bf16(a1L[m], b1[n], acc[m][n], 0, 0, 0);
        __builtin_amdgcn_s_setprio(0);
        asm volatile("s_waitcnt lgkmcnt(0)" ::: "memory");
        if (kt < 63) asm volatile("s_waitcnt vmcnt(4)" ::: "memory");
        __builtin_amdgcn_s_barrier();
        asm volatile("" ::: "memory");

        // ---- P3: stage A0,A1(kt+2)->cur; read a0L(kt+1) from nxt; MFMA G3 = m4-7 x k1
        if (kt + 2 < 64) { STG(cur, pA, 0, kt + 2); STG(cur, pA, 1, kt + 2); }
        if (kt + 1 < 64) {
#pragma unroll
            for (int m = 0; m < 4; ++m) a0n[m] = *(const bf16x8*)&lds[nxt + aB + m * 1024 + c0];
        }
        __builtin_amdgcn_s_setprio(1);
#pragma unroll
        for (int m = 0; m < 4; ++m)
#pragma unroll
            for (int n = 0; n < 4; ++n)
                acc[m + 4][n] = __builtin_amdgcn_mfma_f32_16x16x32_bf16(a1H[m], b1[n], acc[m + 4][n], 0, 0, 0);
        __builtin_amdgcn_s_setprio(0);
        if (kt + 1 < 64) {
#pragma unroll
            for (int m = 0; m < 4; ++m) a0L[m] = a0n[m];
        }
    }
#undef STG

    // epilogue: C row = 16m + 4q + r, col = 16n + rl (m89 layout), NT stores
    const int crow = (bm << 8) + (wm << 7) + (q << 2);
    const int ccol = (bn << 8) + (wn << 6) + rl;
#pragma unroll
    for (int m = 0; m < 8; ++m)
#pragma unroll
        for (int n = 0; n < 4; ++n)
#pragma unroll
            for (int r = 0; r < 4; ++r)
                __builtin_nontemporal_store(acc[m][n][r],
                    &C[(size_t)(crow + m * 16 + r) * 4096 + ccol + n * 16]);
}

extern "C" void kernel_launch(void* const* d_in, const int* in_sizes, int n_in,
                              void* d_out, int out_size, void* d_ws, size_t ws_size,
                              hipStream_t stream) {
    const float* input      = (const float*)d_in[0];
    const float* lora_route = (const float*)d_in[1];
    const float* lora_down  = (const float*)d_in[2];
    const float* W          = (const float*)d_in[3];
    const int*   task_id    = (const int*)d_in[4];

    char* ws = (char*)d_ws;
    bf16*  inbf    = (bf16*)(ws + OFF_INBF);
    bf16*  Wv      = (bf16*)(ws + OFF_WV);
    float* meansum = (float*)(ws + OFF_MEAN);
    int*   info_i  = (int*)(ws + OFF_INFO);
    float* info_f  = (float*)(ws + OFF_INFO);
    float* v       = (float*)(ws + OFF_V);
    // TP/NP overlay Wv (consumed by vbuild before scaleW writes Wv)
    float* TP      = (float*)(ws + OFF_WV);
    float* NP      = TP + TP_ELEMS;
    float* out     = (float*)d_out;

    hipMemsetAsync(meansum, 0, 4096 * 4, stream);

    mean_cvt<<<dim3(4, 128), 256, 0, stream>>>((const float4*)input, meansum, inbf);
    omega_kernel<<<1, 256, 0, stream>>>(meansum, lora_route, task_id, info_i, info_f);
    diag_kernel<<<2048, 256, 0, stream>>>(lora_down, info_i, TP, NP);
    vbuild<<<16, 256, 0, stream>>>(TP, NP, info_i, info_f, v);
    scaleW<<<4096, 256, 0, stream>>>((const float4*)W, v, Wv);
    gemm256<<<256, 512, 0, stream>>>(inbf, Wv, out);
}